// Round 1
// baseline (311.978 us; speedup 1.0000x reference)
//
#include <hip/hip_runtime.h>
#include <hip/hip_bf16.h>

typedef __attribute__((ext_vector_type(8))) short bf16x8;
typedef __attribute__((ext_vector_type(4))) float f32x4;

// ---------------- ws layout ----------------
// F    : bf16 [32768][672]            @ 0          (44,040,192 B)
// W2   : bf16 [768][672]              @ 44,040,192 (1,032,192 B)
// biasT: f32  [768]                   @ 45,072,384 (3,072 B)
// part : f32  [512]                   @ 45,075,456 (2,048 B)
// dmin : f32  [32]                    @ 45,077,504 (128 B)

__device__ __forceinline__ void async_copy16(const void* gsrc, void* ldst) {
    __builtin_amdgcn_global_load_lds(
        (const __attribute__((address_space(1))) void*)gsrc,
        (__attribute__((address_space(3))) void*)ldst,
        16, 0, 0);
}

// -------- per-batch min (two stage) --------
__global__ __launch_bounds__(256) void min_partial_kernel(const float* __restrict__ x,
                                                          float* __restrict__ partial) {
    const int blk = blockIdx.x;           // 512 blocks: 32 batches x 16 chunks
    const int b = blk >> 4, c = blk & 15;
    const float4* p = (const float4*)(x + (size_t)b * 262144 + (size_t)c * 16384);
    float mn = 3.0e38f;
    for (int i = threadIdx.x; i < 4096; i += 256) {
        float4 v = p[i];
        mn = fminf(mn, fminf(fminf(v.x, v.y), fminf(v.z, v.w)));
    }
    #pragma unroll
    for (int off = 32; off > 0; off >>= 1)
        mn = fminf(mn, __shfl_down(mn, off));
    __shared__ float red[4];
    if ((threadIdx.x & 63) == 0) red[threadIdx.x >> 6] = mn;
    __syncthreads();
    if (threadIdx.x == 0)
        partial[blk] = fminf(fminf(red[0], red[1]), fminf(red[2], red[3]));
}

__global__ void min_final_kernel(const float* __restrict__ partial, float* __restrict__ dmin) {
    const int t = threadIdx.x;
    if (t < 32) {
        float mn = 3.0e38f;
        for (int i = 0; i < 16; ++i) mn = fminf(mn, partial[t * 16 + i]);
        dmin[t] = mn;
    }
}

// -------- weight repack: W2[e][k] bf16, k = [g16 dh|g16 mp|g8 dh|g8 mp|g4 dh|g4 mp] --------
__global__ __launch_bounds__(256) void prep_kernel(const float* __restrict__ w0, const float* __restrict__ b0,
                                                   const float* __restrict__ w1, const float* __restrict__ b1,
                                                   const float* __restrict__ w2, const float* __restrict__ b2,
                                                   __hip_bfloat16* __restrict__ W2, float* __restrict__ biasT) {
    const int idx = blockIdx.x * 256 + threadIdx.x;
    if (idx < 768 * 672) {
        const int e = idx / 672, k = idx - e * 672;
        float v;
        if (k < 512)      v = w0[e * 512 + k];          // (2,16,16) flat
        else if (k < 640) v = w1[e * 128 + (k - 512)];  // (2,8,8) flat
        else              v = w2[e * 32  + (k - 640)];  // (2,4,4) flat
        W2[idx] = __float2bfloat16(v);
    }
    if (idx < 768) biasT[idx] = b0[idx] + b1[idx] + b2[idx];
}

// -------- per-patch: pools + BFS fill + feature emit --------
template <int G>
__device__ __forceinline__ void fill_grid(float* fd, int* fv, int t) {
    const bool active = (t < G * G);
    const int y = t / G, x = t % G;
    int v = active ? fv[t] : 1;
    for (;;) {
        float s = 0.f; int cnt = 0;
        if (active && !v) {
            #pragma unroll
            for (int dy = -1; dy <= 1; ++dy) {
                const int ny = y + dy;
                if ((unsigned)ny < (unsigned)G) {
                    #pragma unroll
                    for (int dx = -1; dx <= 1; ++dx) {
                        const int nx = x + dx;
                        if ((unsigned)nx < (unsigned)G) {
                            const int q = ny * G + nx;
                            if (fv[q]) { cnt++; s += fd[q]; }
                        }
                    }
                }
            }
        }
        __syncthreads();                       // reads done before writes
        const int newv = (active && !v && cnt > 0) ? 1 : 0;
        if (newv) { fd[t] = s / (float)cnt; fv[t] = 1; v = 1; }
        if (__syncthreads_count(newv) == 0) break;   // barrier + convergence test
    }
}

__global__ __launch_bounds__(256) void patch_kernel(const float* __restrict__ x,
                                                    const float* __restrict__ dmin,
                                                    __hip_bfloat16* __restrict__ F,
                                                    float* __restrict__ maskout) {
    __shared__ float s_d0[256], s_m0[256], s_fd[256];
    __shared__ int s_fv[256];
    __shared__ float s_d8[64]; __shared__ int s_v8[64];
    __shared__ float s_d4[16]; __shared__ int s_v4[16];

    const int pid = blockIdx.x;               // 32768 patches
    const int b = pid >> 10, n = pid & 1023;
    const int gi = n >> 5, gj = n & 31;
    const int t = threadIdx.x;
    const int ph = t >> 4, pw = t & 15;

    const float thr = dmin[b] + 1e-6f;
    const float d = x[(size_t)(b * 512 + gi * 16 + ph) * 512 + gj * 16 + pw];
    const float m = (d > thr) ? 1.0f : 0.0f;
    s_d0[t] = d * m;
    s_m0[t] = m;
    s_fd[t] = (d * m) / (m + 1e-5f);          // dh at g=16
    s_fv[t] = (m > 0.f) ? 1 : 0;
    const int anym = __syncthreads_count(m > 0.f);   // doubles as init barrier
    if (t == 0) maskout[pid] = anym ? 1.0f : 0.0f;

    fill_grid<16>(s_fd, s_fv, t);
    __hip_bfloat16* Fp = F + (size_t)pid * 672;
    Fp[t]       = __float2bfloat16(s_fd[t]);
    Fp[256 + t] = __float2bfloat16(m);

    // g = 8 (2x2 pool of originals)
    float mp8 = 0.f;
    if (t < 64) {
        const int oh = t >> 3, ow = t & 7;
        const int i0 = (oh * 2) * 16 + ow * 2;
        const float num = s_d0[i0] + s_d0[i0 + 1] + s_d0[i0 + 16] + s_d0[i0 + 17];
        const float cm  = s_m0[i0] + s_m0[i0 + 1] + s_m0[i0 + 16] + s_m0[i0 + 17];
        mp8 = cm * 0.25f;
        s_d8[t] = (num * 0.25f) / (mp8 + 1e-5f);
        s_v8[t] = (mp8 >= 1e-5f) ? 1 : 0;
    }
    __syncthreads();
    fill_grid<8>(s_d8, s_v8, t);
    if (t < 64) {
        Fp[512 + t] = __float2bfloat16(s_d8[t]);
        Fp[576 + t] = __float2bfloat16(mp8);
    }

    // g = 4 (4x4 pool of originals)
    float mp4 = 0.f;
    if (t < 16) {
        const int oh = t >> 2, ow = t & 3;
        float num = 0.f, cm = 0.f;
        #pragma unroll
        for (int yy = 0; yy < 4; ++yy)
            #pragma unroll
            for (int xx = 0; xx < 4; ++xx) {
                const int q = (oh * 4 + yy) * 16 + (ow * 4 + xx);
                num += s_d0[q]; cm += s_m0[q];
            }
        mp4 = cm * (1.f / 16.f);
        s_d4[t] = (num * (1.f / 16.f)) / (mp4 + 1e-5f);
        s_v4[t] = (mp4 >= 1e-5f) ? 1 : 0;
    }
    __syncthreads();
    fill_grid<4>(s_d4, s_v4, t);
    if (t < 16) {
        Fp[640 + t] = __float2bfloat16(s_d4[t]);
        Fp[656 + t] = __float2bfloat16(mp4);
    }
}

// -------- GEMM: out[32768][768] = F[32768][672] @ W2[768][672]^T + biasT --------
// 128x128 tile, BK=32, 4 waves (2x2), each wave 64x64 = 4x4 frags of 16x16x32.
// LDS tiles stored [kc(4)][row(128)][8] bf16 -> frag reads are contiguous 16B/lane.
__global__ __launch_bounds__(256) void gemm_kernel(const short* __restrict__ F,
                                                   const short* __restrict__ W2,
                                                   const float* __restrict__ biasT,
                                                   float* __restrict__ out) {
    constexpr int K = 672, N = 768;
    const int tm = blockIdx.x / 6;
    const int tn = blockIdx.x % 6;
    const int m0 = tm * 128, e0 = tn * 128;
    const int t = threadIdx.x;
    const int wave = t >> 6, lane = t & 63;
    const int wm = wave >> 1, wn = wave & 1;
    const int lg = lane & 15, kc = lane >> 4;

    __shared__ short lds_a[4096];   // [4][128][8]
    __shared__ short lds_b[4096];

    f32x4 acc[4][4];
    const f32x4 zero = {0.f, 0.f, 0.f, 0.f};
    #pragma unroll
    for (int i = 0; i < 4; ++i)
        #pragma unroll
        for (int j = 0; j < 4; ++j) acc[i][j] = zero;

    for (int kb = 0; kb < K; kb += 32) {
        __syncthreads();   // previous iter's reads done before overwrite
        #pragma unroll
        for (int si = 0; si < 2; ++si) {
            const int s = wave * 2 + si;           // 8 slots of 1024B each
            const int row = ((s & 1) << 6) + lane; // tile row
            const int kcc = s >> 1;                // k-chunk (8 bf16)
            async_copy16(F  + (size_t)(m0 + row) * K + kb + kcc * 8, &lds_a[s * 512]);
            async_copy16(W2 + (size_t)(e0 + row) * K + kb + kcc * 8, &lds_b[s * 512]);
        }
        __syncthreads();   // vmcnt(0) drain + barrier: staged data visible

        bf16x8 af[4], bfr[4];
        #pragma unroll
        for (int i = 0; i < 4; ++i) {
            af[i]  = *(const bf16x8*)&lds_a[(kc * 128 + wm * 64 + i * 16 + lg) * 8];
            bfr[i] = *(const bf16x8*)&lds_b[(kc * 128 + wn * 64 + i * 16 + lg) * 8];
        }
        #pragma unroll
        for (int i = 0; i < 4; ++i)
            #pragma unroll
            for (int j = 0; j < 4; ++j)
                acc[i][j] = __builtin_amdgcn_mfma_f32_16x16x32_bf16(af[i], bfr[j], acc[i][j], 0, 0, 0);
    }

    // epilogue: C/D layout col=lane&15, row=(lane>>4)*4+reg (m89-verified)
    const int rbase = (lane >> 4) * 4;
    #pragma unroll
    for (int j = 0; j < 4; ++j) {
        const int e = e0 + wn * 64 + j * 16 + lg;
        const float bs = biasT[e];
        #pragma unroll
        for (int i = 0; i < 4; ++i) {
            const int mr = m0 + wm * 64 + i * 16 + rbase;
            #pragma unroll
            for (int r = 0; r < 4; ++r)
                out[(size_t)(mr + r) * N + e] = acc[i][j][r] + bs;
        }
    }
}

extern "C" void kernel_launch(void* const* d_in, const int* in_sizes, int n_in,
                              void* d_out, int out_size, void* d_ws, size_t ws_size,
                              hipStream_t stream) {
    const float* x  = (const float*)d_in[0];
    const float* w0 = (const float*)d_in[1];
    const float* b0 = (const float*)d_in[2];
    const float* w1 = (const float*)d_in[3];
    const float* b1 = (const float*)d_in[4];
    const float* w2 = (const float*)d_in[5];
    const float* b2 = (const float*)d_in[6];
    float* out = (float*)d_out;

    char* ws = (char*)d_ws;
    __hip_bfloat16* F   = (__hip_bfloat16*)ws;
    __hip_bfloat16* W2  = (__hip_bfloat16*)(ws + 44040192);
    float* biasT        = (float*)(ws + 45072384);
    float* partial      = (float*)(ws + 45075456);
    float* dmin         = (float*)(ws + 45077504);
    float* maskout      = out + 25165824;   // feat is 32*1024*768

    min_partial_kernel<<<512, 256, 0, stream>>>(x, partial);
    min_final_kernel<<<1, 64, 0, stream>>>(partial, dmin);
    prep_kernel<<<2016, 256, 0, stream>>>(w0, b0, w1, b1, w2, b2, W2, biasT);
    patch_kernel<<<32768, 256, 0, stream>>>(x, dmin, F, maskout);
    gemm_kernel<<<1536, 256, 0, stream>>>((const short*)F, (const short*)W2, biasT, out);
}

// Round 2
// 176.718 us; speedup vs baseline: 1.7654x; 1.7654x over previous
//
#include <hip/hip_runtime.h>
#include <hip/hip_bf16.h>

typedef __attribute__((ext_vector_type(8))) short bf16x8;
typedef __attribute__((ext_vector_type(4))) float f32x4;

// ---------------- ws layout ----------------
// F    : bf16 [32768][672]            @ 0          (44,040,192 B)
// W2   : bf16 [768][672]              @ 44,040,192 (1,032,192 B)
// biasT: f32  [768]                   @ 45,072,384 (3,072 B)
// part : f32  [512]                   @ 45,075,456 (2,048 B)
// dmin : f32  [32]                    @ 45,077,504 (128 B)

__device__ __forceinline__ void async_copy16(const void* gsrc, void* ldst) {
    __builtin_amdgcn_global_load_lds(
        (const __attribute__((address_space(1))) void*)gsrc,
        (__attribute__((address_space(3))) void*)ldst,
        16, 0, 0);
}

__device__ __forceinline__ unsigned short f2bf(float f) {  // RNE, matches __float2bfloat16
    unsigned u = __float_as_uint(f);
    u += 0x7FFFu + ((u >> 16) & 1u);
    return (unsigned short)(u >> 16);
}

// -------- per-batch min (two stage) --------
__global__ __launch_bounds__(256) void min_partial_kernel(const float* __restrict__ x,
                                                          float* __restrict__ partial) {
    const int blk = blockIdx.x;           // 512 blocks: 32 batches x 16 chunks
    const int b = blk >> 4, c = blk & 15;
    const float4* p = (const float4*)(x + (size_t)b * 262144 + (size_t)c * 16384);
    float mn = 3.0e38f;
    for (int i = threadIdx.x; i < 4096; i += 256) {
        float4 v = p[i];
        mn = fminf(mn, fminf(fminf(v.x, v.y), fminf(v.z, v.w)));
    }
    #pragma unroll
    for (int off = 32; off > 0; off >>= 1)
        mn = fminf(mn, __shfl_down(mn, off));
    __shared__ float red[4];
    if ((threadIdx.x & 63) == 0) red[threadIdx.x >> 6] = mn;
    __syncthreads();
    if (threadIdx.x == 0)
        partial[blk] = fminf(fminf(red[0], red[1]), fminf(red[2], red[3]));
}

__global__ void min_final_kernel(const float* __restrict__ partial, float* __restrict__ dmin) {
    const int t = threadIdx.x;
    if (t < 32) {
        float mn = 3.0e38f;
        for (int i = 0; i < 16; ++i) mn = fminf(mn, partial[t * 16 + i]);
        dmin[t] = mn;
    }
}

// -------- weight repack: W2[e][k] bf16, k = [g16 dh|g16 mp|g8 dh|g8 mp|g4 dh|g4 mp] --------
__global__ __launch_bounds__(256) void prep_kernel(const float* __restrict__ w0, const float* __restrict__ b0,
                                                   const float* __restrict__ w1, const float* __restrict__ b1,
                                                   const float* __restrict__ w2, const float* __restrict__ b2,
                                                   __hip_bfloat16* __restrict__ W2, float* __restrict__ biasT) {
    const int idx = blockIdx.x * 256 + threadIdx.x;
    if (idx < 768 * 672) {
        const int e = idx / 672, k = idx - e * 672;
        float v;
        if (k < 512)      v = w0[e * 512 + k];          // (2,16,16) flat
        else if (k < 640) v = w1[e * 128 + (k - 512)];  // (2,8,8) flat
        else              v = w2[e * 32  + (k - 640)];  // (2,4,4) flat
        W2[idx] = __float2bfloat16(v);
    }
    if (idx < 768) biasT[idx] = b0[idx] + b1[idx] + b2[idx];
}

// -------- per-patch: one WAVE per patch, no __syncthreads in the fill --------
// invalid cells encoded as -1.0f; sel = fmaxf(v,0), cnt += (v>=0).
// Within-wave LDS ordering: all window reads precede update writes in program
// order; LDS is in-order per wave -> no barrier needed. Convergence via __any.
__global__ __launch_bounds__(256) void patch_kernel(const float* __restrict__ x,
                                                    const float* __restrict__ dmin,
                                                    __hip_bfloat16* __restrict__ F,
                                                    float* __restrict__ maskout) {
    __shared__ float s_d0[4][256];
    __shared__ float s_m0[4][256];
    __shared__ float s_fd[4][256];
    __shared__ float s_f8[4][64];
    __shared__ float s_f4[4][16];

    const int t = threadIdx.x;
    const int pid0 = blockIdx.x * 4;          // 4 horizontally-adjacent patches
    const int b = pid0 >> 10;
    const int n0 = pid0 & 1023;
    const int gi = n0 >> 5, gj0 = n0 & 31;
    const float thr = dmin[b] + 1e-6f;

    // coalesced cooperative load: 16 rows x 64 cols (4 patches)
    {
        const int pr = t >> 4, ck = t & 15;
        const float4 v = *(const float4*)(x + ((size_t)(b * 512 + gi * 16 + pr)) * 512 + gj0 * 16 + ck * 4);
        const int p = ck >> 2;
        const int ci = pr * 16 + (ck & 3) * 4;
        const float dv[4] = {v.x, v.y, v.z, v.w};
        #pragma unroll
        for (int j = 0; j < 4; ++j) {
            const float d = dv[j];
            const float m = (d > thr) ? 1.0f : 0.0f;
            s_d0[p][ci + j] = d * m;
            s_m0[p][ci + j] = m;
            // dh16 = (d*m)/(m+1e-5): m==1 -> d/1.00001; invalid -> -1 sentinel
            s_fd[p][ci + j] = (m > 0.f) ? d * (1.0f / 1.00001f) : -1.0f;
        }
    }
    __syncthreads();   // the ONLY block barrier

    const int w = t >> 6, lane = t & 63;
    const int pid = pid0 + w;
    float* fd = s_fd[w];
    float* d0 = s_d0[w];
    float* m0 = s_m0[w];
    float* f8 = s_f8[w];
    float* f4 = s_f4[w];
    unsigned short* Fp = (unsigned short*)(F + (size_t)pid * 672);

    // ---- g16 fill: 4 contiguous cells/lane, shared 3x6 window ----
    const int row = lane >> 2, cq = lane & 3, cg = cq * 4;
    const float4* fdv = (const float4*)fd;
    for (;;) {
        float colS[6], colN[6];
        #pragma unroll
        for (int c = 0; c < 6; ++c) { colS[c] = 0.f; colN[c] = 0.f; }
        float myv[4];
        #pragma unroll
        for (int dr = 0; dr < 3; ++dr) {
            const int r = row - 1 + dr;
            if ((unsigned)r < 16u) {
                const float4 mid = fdv[r * 4 + cq];
                const float lft = (cg > 0)  ? fd[r * 16 + cg - 1] : -1.f;
                const float rgt = (cg < 12) ? fd[r * 16 + cg + 4] : -1.f;
                const float vv[6] = {lft, mid.x, mid.y, mid.z, mid.w, rgt};
                if (dr == 1) { myv[0] = mid.x; myv[1] = mid.y; myv[2] = mid.z; myv[3] = mid.w; }
                #pragma unroll
                for (int c = 0; c < 6; ++c) {
                    colS[c] += fmaxf(vv[c], 0.f);
                    colN[c] += (vv[c] >= 0.f) ? 1.f : 0.f;
                }
            }
        }
        float nv[4];
        int wmask = 0;
        #pragma unroll
        for (int j = 0; j < 4; ++j) {
            if (myv[j] < 0.f) {
                const float N = colN[j] + colN[j + 1] + colN[j + 2];
                if (N > 0.f) {
                    nv[j] = (colS[j] + colS[j + 1] + colS[j + 2]) / N;
                    wmask |= (1 << j);
                }
            }
        }
        const bool any = __any(wmask != 0);
        #pragma unroll
        for (int j = 0; j < 4; ++j)
            if (wmask & (1 << j)) fd[row * 16 + cg + j] = nv[j];
        if (!any) break;
    }
    // emit g16 dh + mask (packed 4x bf16 = 8B stores)
    {
        const int co = row * 16 + cg;
        const float4 fin = fdv[row * 4 + cq];
        ushort4 o;
        o.x = f2bf(fmaxf(fin.x, 0.f)); o.y = f2bf(fmaxf(fin.y, 0.f));
        o.z = f2bf(fmaxf(fin.z, 0.f)); o.w = f2bf(fmaxf(fin.w, 0.f));
        *(ushort4*)(Fp + co) = o;
        const float4 mm = *(const float4*)&m0[co];
        ushort4 om;
        om.x = f2bf(mm.x); om.y = f2bf(mm.y); om.z = f2bf(mm.z); om.w = f2bf(mm.w);
        *(ushort4*)(Fp + 256 + co) = om;
    }

    // ---- g8 pool + fill: 1 cell/lane ----
    const int oh8 = lane >> 3, ow8 = lane & 7;
    float mp8;
    {
        const int i0 = oh8 * 32 + ow8 * 2;
        const float num = d0[i0] + d0[i0 + 1] + d0[i0 + 16] + d0[i0 + 17];
        const float cm  = m0[i0] + m0[i0 + 1] + m0[i0 + 16] + m0[i0 + 17];
        mp8 = cm * 0.25f;
        const float dh = (num * 0.25f) / (mp8 + 1e-5f);
        f8[lane] = (mp8 >= 1e-5f) ? dh : -1.f;
    }
    for (;;) {
        const float mine = f8[lane];
        float nv = 0.f; bool wr = false;
        if (mine < 0.f) {
            float S = 0.f, N = 0.f;
            #pragma unroll
            for (int dr = -1; dr <= 1; ++dr) {
                const int r = oh8 + dr;
                if ((unsigned)r < 8u) {
                    #pragma unroll
                    for (int dc = -1; dc <= 1; ++dc) {
                        const int c = ow8 + dc;
                        if ((unsigned)c < 8u) {
                            const float u = f8[r * 8 + c];
                            S += fmaxf(u, 0.f);
                            N += (u >= 0.f) ? 1.f : 0.f;
                        }
                    }
                }
            }
            if (N > 0.f) { nv = S / N; wr = true; }
        }
        const bool any = __any(wr);
        if (wr) f8[lane] = nv;
        if (!any) break;
    }
    Fp[512 + lane] = f2bf(fmaxf(f8[lane], 0.f));
    Fp[576 + lane] = f2bf(mp8);

    // ---- g4 pool + fill: lanes 0..15 ----
    float mp4 = 0.f;
    if (lane < 16) {
        const int oh = lane >> 2, ow = lane & 3;
        float num = 0.f, cm = 0.f;
        #pragma unroll
        for (int yy = 0; yy < 4; ++yy)
            #pragma unroll
            for (int xx = 0; xx < 4; ++xx) {
                const int q = (oh * 4 + yy) * 16 + (ow * 4 + xx);
                num += d0[q]; cm += m0[q];
            }
        mp4 = cm * (1.f / 16.f);
        const float dh = (num * (1.f / 16.f)) / (mp4 + 1e-5f);
        f4[lane] = (mp4 >= 1e-5f) ? dh : -1.f;
    }
    for (;;) {
        float nv = 0.f; bool wr = false;
        if (lane < 16 && f4[lane] < 0.f) {
            const int oh = lane >> 2, ow = lane & 3;
            float S = 0.f, N = 0.f;
            #pragma unroll
            for (int dr = -1; dr <= 1; ++dr) {
                const int r = oh + dr;
                if ((unsigned)r < 4u) {
                    #pragma unroll
                    for (int dc = -1; dc <= 1; ++dc) {
                        const int c = ow + dc;
                        if ((unsigned)c < 4u) {
                            const float u = f4[r * 4 + c];
                            S += fmaxf(u, 0.f);
                            N += (u >= 0.f) ? 1.f : 0.f;
                        }
                    }
                }
            }
            if (N > 0.f) { nv = S / N; wr = true; }
        }
        const bool any = __any(wr);
        if (wr) f4[lane] = nv;
        if (!any) break;
    }
    if (lane < 16) {
        Fp[640 + lane] = f2bf(fmaxf(f4[lane], 0.f));
        Fp[656 + lane] = f2bf(mp4);
    }
    const unsigned long long bal = __ballot(lane < 16 && mp4 > 0.f);
    if (lane == 0) maskout[pid] = bal ? 1.0f : 0.0f;
}

// -------- GEMM: out[32768][768] = F[32768][672] @ W2[768][672]^T + biasT --------
__global__ __launch_bounds__(256) void gemm_kernel(const short* __restrict__ F,
                                                   const short* __restrict__ W2,
                                                   const float* __restrict__ biasT,
                                                   float* __restrict__ out) {
    constexpr int K = 672, N = 768;
    const int tm = blockIdx.x / 6;
    const int tn = blockIdx.x % 6;
    const int m0 = tm * 128, e0 = tn * 128;
    const int t = threadIdx.x;
    const int wave = t >> 6, lane = t & 63;
    const int wm = wave >> 1, wn = wave & 1;
    const int lg = lane & 15, kc = lane >> 4;

    __shared__ short lds_a[4096];   // [4][128][8]
    __shared__ short lds_b[4096];

    f32x4 acc[4][4];
    const f32x4 zero = {0.f, 0.f, 0.f, 0.f};
    #pragma unroll
    for (int i = 0; i < 4; ++i)
        #pragma unroll
        for (int j = 0; j < 4; ++j) acc[i][j] = zero;

    for (int kb = 0; kb < K; kb += 32) {
        __syncthreads();
        #pragma unroll
        for (int si = 0; si < 2; ++si) {
            const int s = wave * 2 + si;
            const int row = ((s & 1) << 6) + lane;
            const int kcc = s >> 1;
            async_copy16(F  + (size_t)(m0 + row) * K + kb + kcc * 8, &lds_a[s * 512]);
            async_copy16(W2 + (size_t)(e0 + row) * K + kb + kcc * 8, &lds_b[s * 512]);
        }
        __syncthreads();

        bf16x8 af[4], bfr[4];
        #pragma unroll
        for (int i = 0; i < 4; ++i) {
            af[i]  = *(const bf16x8*)&lds_a[(kc * 128 + wm * 64 + i * 16 + lg) * 8];
            bfr[i] = *(const bf16x8*)&lds_b[(kc * 128 + wn * 64 + i * 16 + lg) * 8];
        }
        #pragma unroll
        for (int i = 0; i < 4; ++i)
            #pragma unroll
            for (int j = 0; j < 4; ++j)
                acc[i][j] = __builtin_amdgcn_mfma_f32_16x16x32_bf16(af[i], bfr[j], acc[i][j], 0, 0, 0);
    }

    const int rbase = (lane >> 4) * 4;
    #pragma unroll
    for (int j = 0; j < 4; ++j) {
        const int e = e0 + wn * 64 + j * 16 + lg;
        const float bs = biasT[e];
        #pragma unroll
        for (int i = 0; i < 4; ++i) {
            const int mr = m0 + wm * 64 + i * 16 + rbase;
            #pragma unroll
            for (int r = 0; r < 4; ++r)
                out[(size_t)(mr + r) * N + e] = acc[i][j][r] + bs;
        }
    }
}

extern "C" void kernel_launch(void* const* d_in, const int* in_sizes, int n_in,
                              void* d_out, int out_size, void* d_ws, size_t ws_size,
                              hipStream_t stream) {
    const float* x  = (const float*)d_in[0];
    const float* w0 = (const float*)d_in[1];
    const float* b0 = (const float*)d_in[2];
    const float* w1 = (const float*)d_in[3];
    const float* b1 = (const float*)d_in[4];
    const float* w2 = (const float*)d_in[5];
    const float* b2 = (const float*)d_in[6];
    float* out = (float*)d_out;

    char* ws = (char*)d_ws;
    __hip_bfloat16* F   = (__hip_bfloat16*)ws;
    __hip_bfloat16* W2  = (__hip_bfloat16*)(ws + 44040192);
    float* biasT        = (float*)(ws + 45072384);
    float* partial      = (float*)(ws + 45075456);
    float* dmin         = (float*)(ws + 45077504);
    float* maskout      = out + 25165824;   // feat is 32*1024*768

    min_partial_kernel<<<512, 256, 0, stream>>>(x, partial);
    min_final_kernel<<<1, 64, 0, stream>>>(partial, dmin);
    prep_kernel<<<2016, 256, 0, stream>>>(w0, b0, w1, b1, w2, b2, W2, biasT);
    patch_kernel<<<8192, 256, 0, stream>>>(x, dmin, F, maskout);
    gemm_kernel<<<1536, 256, 0, stream>>>((const short*)F, (const short*)W2, biasT, out);
}